// Round 4
// baseline (4631.218 us; speedup 1.0000x reference)
//
#include <hip/hip_runtime.h>
#include <hip/hip_bf16.h>
#include <math.h>

typedef __hip_bfloat16 bf16;

#define TOKENS 50176        // 16 * 3136
#define CW 128              // windows per chunk (8 chunks)
#define CROWS (CW * 49)     // 6272 rows per chunk
#define SCALE_ 0.17677669529663687f  // 32^-0.5

__device__ __forceinline__ float b2f(bf16 v) { return __bfloat162float(v); }
__device__ __forceinline__ bf16  f2b(float v) { return __float2bfloat16(v); }

// ---------------- LN1 + cyclic shift(-3,+3) + window partition (chunk) ----------------
// fp32 in -> bf16 wins chunk
__global__ __launch_bounds__(64) void ln1_kernel(const float* __restrict__ x,
                                                 const float* __restrict__ g,
                                                 const float* __restrict__ bta,
                                                 bf16* __restrict__ wins_c,
                                                 int w_base) {
  int tl = blockIdx.x;             // 0..CROWS-1 (chunk-local row)
  int lane = threadIdx.x;
  int wloc = tl / 49, n = tl - wloc * 49;
  int w = w_base + wloc;           // global window
  int bi = w >> 6, wi = w & 63;
  int hw = wi >> 3, ww = wi & 7;
  int ti = n / 7, tj = n - ti * 7;
  int hr = hw * 7 + ti, wr = ww * 7 + tj;     // coords in rolled image
  int hs = (hr + 3) % 56;                     // roll shift=-3 on axis 1
  int wsc = (wr + 53) % 56;                   // roll shift=+3 on axis 2
  const float* row = x + ((size_t)bi * 3136 + hs * 56 + wsc) * 384;
  float v[6];
  float s = 0.f, s2 = 0.f;
#pragma unroll
  for (int j = 0; j < 6; ++j) {
    v[j] = row[lane + 64 * j];
    s += v[j]; s2 += v[j] * v[j];
  }
#pragma unroll
  for (int m = 32; m >= 1; m >>= 1) {
    s  += __shfl_xor(s, m, 64);
    s2 += __shfl_xor(s2, m, 64);
  }
  float mu = s * (1.f / 384.f);
  float var = s2 * (1.f / 384.f) - mu * mu;
  float rstd = rsqrtf(var + 1e-3f);
  bf16* orow = wins_c + (size_t)tl * 384;
#pragma unroll
  for (int j = 0; j < 6; ++j) {
    int c = lane + 64 * j;
    orow[c] = f2b((v[j] - mu) * rstd * g[c] + bta[c]);
  }
}

// ---------------- LN2: fp32 x1 rows -> bf16 ----------------
__global__ __launch_bounds__(64) void ln2_kernel(const float* __restrict__ x1,
                                                 const float* __restrict__ g,
                                                 const float* __restrict__ bta,
                                                 bf16* __restrict__ out) {
  int t = blockIdx.x;
  int lane = threadIdx.x;
  const float* row = x1 + (size_t)t * 384;
  float v[6];
  float s = 0.f, s2 = 0.f;
#pragma unroll
  for (int j = 0; j < 6; ++j) {
    v[j] = row[lane + 64 * j];
    s += v[j]; s2 += v[j] * v[j];
  }
#pragma unroll
  for (int m = 32; m >= 1; m >>= 1) {
    s  += __shfl_xor(s, m, 64);
    s2 += __shfl_xor(s2, m, 64);
  }
  float mu = s * (1.f / 384.f);
  float var = s2 * (1.f / 384.f) - mu * mu;
  float rstd = rsqrtf(var + 1e-3f);
  bf16* orow = out + (size_t)t * 384;
#pragma unroll
  for (int j = 0; j < 6; ++j) {
    int c = lane + 64 * j;
    orow[c] = f2b((v[j] - mu) * rstd * g[c] + bta[c]);
  }
}

// ---------------- GEMM: C = A[rows,K](bf16) @ B[K,N](fp32) + bias(fp32) ----------------
// MODE 0: qkv  -> bf16 Cout
// MODE 1: proj -> window-reverse + roll(+3,+3) scatter + residual(x fp32) -> fp32 d_out (x1)
// MODE 2: mlp1 -> gelu -> bf16
// MODE 3: mlp2 -> + bias + resid fp32 -> fp32 Cout (in-place with resid allowed)
template<int MODE>
__global__ __launch_bounds__(256) void gemm_kernel(
    const bf16* __restrict__ A, const float* __restrict__ Bm,
    const float* __restrict__ bias, int N, int K, int row_base,
    const float* __restrict__ resid, void* __restrict__ Cout_) {
  __shared__ float As[16][65];
  __shared__ float Bs[16][65];
  int tid = threadIdx.x;
  int ty = tid >> 4, tx = tid & 15;
  int row0 = blockIdx.x * 64, col0 = blockIdx.y * 64;
  float acc[4][4] = {};
  for (int k0 = 0; k0 < K; k0 += 16) {
    {
      int m = tid >> 2, kq = (tid & 3) * 4;
      const bf16* src = A + (size_t)(row0 + m) * K + k0 + kq;
#pragma unroll
      for (int u = 0; u < 4; ++u) As[kq + u][m] = b2f(src[u]);
      int kk = tid >> 4, nq = (tid & 15) * 4;
      const float* srcb = Bm + (size_t)(k0 + kk) * N + col0 + nq;
#pragma unroll
      for (int u = 0; u < 4; ++u) Bs[kk][nq + u] = srcb[u];
    }
    __syncthreads();
#pragma unroll
    for (int k = 0; k < 16; ++k) {
      float a[4], b[4];
#pragma unroll
      for (int i = 0; i < 4; ++i) a[i] = As[k][ty * 4 + i];
#pragma unroll
      for (int j = 0; j < 4; ++j) b[j] = Bs[k][tx * 4 + j];
#pragma unroll
      for (int i = 0; i < 4; ++i)
#pragma unroll
        for (int j = 0; j < 4; ++j) acc[i][j] += a[i] * b[j];
    }
    __syncthreads();
  }
#pragma unroll
  for (int i = 0; i < 4; ++i) {
    int r = row0 + ty * 4 + i;
    if (MODE == 0) {
      bf16* C = (bf16*)Cout_;
#pragma unroll
      for (int j = 0; j < 4; ++j) {
        int c = col0 + tx * 4 + j;
        C[(size_t)r * N + c] = f2b(acc[i][j] + bias[c]);
      }
    } else if (MODE == 1) {
      float* C = (float*)Cout_;
      int rg = row_base + r;
      int w = rg / 49, n = rg - w * 49;
      int bi = w >> 6, wi = w & 63;
      int hw = wi >> 3, ww = wi & 7;
      int ti = n / 7, tj = n - ti * 7;
      int hr = hw * 7 + ti, wr = ww * 7 + tj;
      int hf = (hr + 3) % 56, wf = (wr + 3) % 56;   // reverse roll(+3,+3), faithful
      size_t p = (size_t)bi * 3136 + hf * 56 + wf;
#pragma unroll
      for (int j = 0; j < 4; ++j) {
        int c = col0 + tx * 4 + j;
        C[p * 384 + c] = acc[i][j] + bias[c] + resid[p * 384 + c];
      }
    } else if (MODE == 2) {
      bf16* C = (bf16*)Cout_;
#pragma unroll
      for (int j = 0; j < 4; ++j) {
        int c = col0 + tx * 4 + j;
        float v = acc[i][j] + bias[c];
        v = 0.5f * v * (1.f + erff(v * 0.7071067811865475f));
        C[(size_t)r * N + c] = f2b(v);
      }
    } else {
      float* C = (float*)Cout_;
#pragma unroll
      for (int j = 0; j < 4; ++j) {
        int c = col0 + tx * 4 + j;
        C[(size_t)r * N + c] = acc[i][j] + bias[c] + resid[(size_t)r * 384 + c];
      }
    }
  }
}

// ---------------- attention per (window, head), chunk-local ----------------
__global__ __launch_bounds__(256) void attn_kernel(const bf16* __restrict__ qkv_c,
                                                   const float* __restrict__ table,
                                                   bf16* __restrict__ attn_c,
                                                   int w_base) {
  int wh = blockIdx.x;                 // 0..CW*12-1
  int wl = wh / 12, h = wh - wl * 12;  // wl chunk-local
  int w = w_base + wl;                 // global window (for mask coords)
  int wi = w & 63;
  int hw = wi >> 3, ww = wi & 7;
  __shared__ float Qs[49][32], Ks[49][32], Vs[49][32];
  __shared__ float S[49][50];
  int tid = threadIdx.x;
  const bf16* base = qkv_c + (size_t)wl * 49 * 1152 + h * 32;
  for (int idx = tid; idx < 1568; idx += 256) {
    int n = idx >> 5, d = idx & 31;
    const bf16* rowp = base + (size_t)n * 1152 + d;
    Qs[n][d] = b2f(rowp[0]);
    Ks[n][d] = b2f(rowp[384]);
    Vs[n][d] = b2f(rowp[768]);
  }
  __syncthreads();
  for (int e = tid; e < 2401; e += 256) {
    int i = e / 49, j = e - i * 49;
    float dot = 0.f;
#pragma unroll
    for (int d = 0; d < 32; ++d) dot += Qs[i][d] * Ks[j][d];
    int yi = i / 7, xi = i - yi * 7;
    int yj = j / 7, xj = j - yj * 7;
    int ridx = (yi - yj + 6) * 13 + (xi - xj + 6);
    float bias = table[ridx * 12 + h];
    int hri = hw * 7 + yi, wri = ww * 7 + xi;
    int hrj = hw * 7 + yj, wrj = ww * 7 + xj;
    int ri = (hri < 49 ? 0 : (hri < 53 ? 1 : 2)) * 3 + (wri < 49 ? 0 : (wri < 53 ? 1 : 2));
    int rj = (hrj < 49 ? 0 : (hrj < 53 ? 1 : 2)) * 3 + (wrj < 49 ? 0 : (wrj < 53 ? 1 : 2));
    float mask = (ri == rj) ? 0.f : -100.f;
    S[i][j] = SCALE_ * dot + bias + mask;
  }
  __syncthreads();
  if (tid < 49) {
    float mx = -1e30f;
    for (int j = 0; j < 49; ++j) mx = fmaxf(mx, S[tid][j]);
    float sum = 0.f;
    for (int j = 0; j < 49; ++j) { float e = expf(S[tid][j] - mx); S[tid][j] = e; sum += e; }
    float inv = 1.f / sum;
    for (int j = 0; j < 49; ++j) S[tid][j] *= inv;
  }
  __syncthreads();
  for (int e = tid; e < 1568; e += 256) {
    int n = e >> 5, d = e & 31;
    float o = 0.f;
    for (int j = 0; j < 49; ++j) o += S[n][j] * Vs[j][d];
    attn_c[((size_t)wl * 49 + n) * 384 + h * 32 + d] = f2b(o);
  }
}

extern "C" void kernel_launch(void* const* d_in, const int* in_sizes, int n_in,
                              void* d_out, int out_size, void* d_ws, size_t ws_size,
                              hipStream_t stream) {
  const float* x      = (const float*)d_in[0];
  const float* ln1_g  = (const float*)d_in[1];
  const float* ln1_b  = (const float*)d_in[2];
  const float* ln2_g  = (const float*)d_in[3];
  const float* ln2_b  = (const float*)d_in[4];
  const float* qkv_w  = (const float*)d_in[5];
  const float* qkv_b  = (const float*)d_in[6];
  const float* proj_w = (const float*)d_in[7];
  const float* proj_b = (const float*)d_in[8];
  const float* mlp_w1 = (const float*)d_in[9];
  const float* mlp_b1 = (const float*)d_in[10];
  const float* mlp_w2 = (const float*)d_in[11];
  const float* mlp_b2 = (const float*)d_in[12];
  const float* rel_tb = (const float*)d_in[13];

  char* ws = (char*)d_ws;
  // Peak workspace: 24,084,480 bytes (bf16 staging only).
  bf16* buf0 = (bf16*)(ws + 0);            // 4,816,896 B: wins_c/attn_c (A), ln2o_c (B)
  bf16* buf1 = (bf16*)(ws + 4816896ull);   // 19,267,584 B: qkv_c (A), hidden_c (B)
  float* out = (float*)d_out;              // fp32; doubles as x1 residual stream

  // ---- Phase A: LN1 -> QKV -> attention -> proj(+scatter+residual), 8 window-chunks
  for (int c = 0; c < 8; ++c) {
    int w_base = c * CW;
    int row_base = w_base * 49;
    ln1_kernel<<<CROWS, 64, 0, stream>>>(x, ln1_g, ln1_b, buf0, w_base);
    gemm_kernel<0><<<dim3(CROWS / 64, 18), 256, 0, stream>>>(
        buf0, qkv_w, qkv_b, 1152, 384, 0, nullptr, (void*)buf1);
    attn_kernel<<<CW * 12, 256, 0, stream>>>(buf1, rel_tb, buf0, w_base);  // in-place over wins_c
    gemm_kernel<1><<<dim3(CROWS / 64, 6), 256, 0, stream>>>(
        buf0, proj_w, proj_b, 384, 384, row_base, x, (void*)out);  // x1 -> d_out (scatter, fp32)
  }

  // ---- Phase B: LN2 -> MLP1(gelu) -> MLP2(+residual), 8 token-chunks (in-place on d_out)
  for (int c = 0; c < 8; ++c) {
    const float* x1c = out + (size_t)c * CROWS * 384;
    float* oc = out + (size_t)c * CROWS * 384;
    ln2_kernel<<<CROWS, 64, 0, stream>>>(x1c, ln2_g, ln2_b, buf0);
    gemm_kernel<2><<<dim3(CROWS / 64, 24), 256, 0, stream>>>(
        buf0, mlp_w1, mlp_b1, 1536, 384, 0, nullptr, (void*)buf1);
    gemm_kernel<3><<<dim3(CROWS / 64, 6), 256, 0, stream>>>(
        buf1, mlp_w2, mlp_b2, 384, 1536, 0, x1c, (void*)oc);
  }
}

// Round 5
// 954.255 us; speedup vs baseline: 4.8532x; 4.8532x over previous
//
#include <hip/hip_runtime.h>
#include <hip/hip_bf16.h>
#include <math.h>

typedef __hip_bfloat16 bf16;
typedef unsigned short ushort_t;
typedef __bf16 bf16x8 __attribute__((ext_vector_type(8)));
typedef float f32x4 __attribute__((ext_vector_type(4)));

#define TOKENS 50176        // 16 * 3136
#define CW2 512             // windows per chunk (2 chunks)
#define CROWS2 (CW2 * 49)   // 25088 rows per chunk
#define SCALE_ 0.17677669529663687f  // 32^-0.5

__device__ __forceinline__ float b2f(bf16 v) { return __bfloat162float(v); }
__device__ __forceinline__ bf16  f2b(float v) { return __float2bfloat16(v); }

// ---------------- weight convert: Wt[n][k] = bf16(W[k][n]) ----------------
__global__ __launch_bounds__(256) void wt_bf16(const float* __restrict__ W,
                                               ushort_t* __restrict__ Wt,
                                               int K, int N) {
  int idx = blockIdx.x * 256 + threadIdx.x;
  if (idx >= K * N) return;
  int n = idx / K, k = idx - n * K;
  bf16 h = f2b(W[(size_t)k * N + n]);
  Wt[idx] = *(ushort_t*)&h;
}

// ---------------- LN1 + cyclic shift(-3,+3) + window partition (full) ----------------
__global__ __launch_bounds__(64) void ln1_kernel(const float* __restrict__ x,
                                                 const float* __restrict__ g,
                                                 const float* __restrict__ bta,
                                                 bf16* __restrict__ wins) {
  int t = blockIdx.x;              // 0..TOKENS-1 (w*49+n)
  int lane = threadIdx.x;
  int w = t / 49, n = t - w * 49;
  int bi = w >> 6, wi = w & 63;
  int hw = wi >> 3, ww = wi & 7;
  int ti = n / 7, tj = n - ti * 7;
  int hr = hw * 7 + ti, wr = ww * 7 + tj;
  int hs = (hr + 3) % 56;          // roll -3 on h
  int wsc = (wr + 53) % 56;        // roll +3 on w
  const float* row = x + ((size_t)bi * 3136 + hs * 56 + wsc) * 384;
  float v[6];
  float s = 0.f, s2 = 0.f;
#pragma unroll
  for (int j = 0; j < 6; ++j) {
    v[j] = row[lane + 64 * j];
    s += v[j]; s2 += v[j] * v[j];
  }
#pragma unroll
  for (int m = 32; m >= 1; m >>= 1) {
    s  += __shfl_xor(s, m, 64);
    s2 += __shfl_xor(s2, m, 64);
  }
  float mu = s * (1.f / 384.f);
  float var = s2 * (1.f / 384.f) - mu * mu;
  float rstd = rsqrtf(var + 1e-3f);
  bf16* orow = wins + (size_t)t * 384;
#pragma unroll
  for (int j = 0; j < 6; ++j) {
    int c = lane + 64 * j;
    orow[c] = f2b((v[j] - mu) * rstd * g[c] + bta[c]);
  }
}

// ---------------- LN2: fp32 rows -> bf16 ----------------
__global__ __launch_bounds__(64) void ln2_kernel(const float* __restrict__ x1,
                                                 const float* __restrict__ g,
                                                 const float* __restrict__ bta,
                                                 bf16* __restrict__ out) {
  int t = blockIdx.x;
  int lane = threadIdx.x;
  const float* row = x1 + (size_t)t * 384;
  float v[6];
  float s = 0.f, s2 = 0.f;
#pragma unroll
  for (int j = 0; j < 6; ++j) {
    v[j] = row[lane + 64 * j];
    s += v[j]; s2 += v[j] * v[j];
  }
#pragma unroll
  for (int m = 32; m >= 1; m >>= 1) {
    s  += __shfl_xor(s, m, 64);
    s2 += __shfl_xor(s2, m, 64);
  }
  float mu = s * (1.f / 384.f);
  float var = s2 * (1.f / 384.f) - mu * mu;
  float rstd = rsqrtf(var + 1e-3f);
  bf16* orow = out + (size_t)t * 384;
#pragma unroll
  for (int j = 0; j < 6; ++j) {
    int c = lane + 64 * j;
    orow[c] = f2b((v[j] - mu) * rstd * g[c] + bta[c]);
  }
}

// ---------------- MFMA GEMM: C[M,N] = A[M,K](bf16) @ Bt[N,K](bf16)^T + bias ----------------
// 128x128 tile, BK=32, 4 waves (2x2), each wave 64x64 via 4x4 mfma_f32_16x16x32_bf16.
// MODE 0: qkv  -> bf16 C[m*N+n]
// MODE 1: proj -> window-reverse + roll(+3,+3) scatter + residual(fp32 x) -> fp32 out
// MODE 2: mlp1 -> gelu -> bf16
// MODE 3: mlp2 -> + bias + resid fp32 -> fp32 out (in-place with resid OK)
template<int MODE>
__global__ __launch_bounds__(256) void mfma_gemm(
    const ushort_t* __restrict__ A, const ushort_t* __restrict__ Bt,
    const float* __restrict__ bias, int N, int K,
    const float* __restrict__ resid, void* __restrict__ out_) {
  __shared__ ushort_t As[128 * 40];   // +8 pad: row stride 40 elems (80B) -> 2-way bank alias (free)
  __shared__ ushort_t Bs[128 * 40];
  int tid = threadIdx.x;
  int lane = tid & 63, wv = tid >> 6;
  int wm = wv >> 1, wn = wv & 1;
  int lm = lane & 15, kg = lane >> 4;      // fragment indices
  int row0 = blockIdx.x * 128, col0 = blockIdx.y * 128;
  f32x4 acc[4][4];
#pragma unroll
  for (int i = 0; i < 4; ++i)
#pragma unroll
    for (int j = 0; j < 4; ++j) acc[i][j] = (f32x4){0.f, 0.f, 0.f, 0.f};

  for (int k0 = 0; k0 < K; k0 += 32) {
#pragma unroll
    for (int it = 0; it < 2; ++it) {
      int lin = it * 256 + tid;            // 0..511
      int r = lin >> 2, kq = (lin & 3) * 8;
      *(int4*)&As[r * 40 + kq] = *(const int4*)&A[(size_t)(row0 + r) * K + k0 + kq];
      *(int4*)&Bs[r * 40 + kq] = *(const int4*)&Bt[(size_t)(col0 + r) * K + k0 + kq];
    }
    __syncthreads();
    bf16x8 a[4], b[4];
#pragma unroll
    for (int i = 0; i < 4; ++i) {
      a[i] = *(const bf16x8*)&As[(wm * 64 + i * 16 + lm) * 40 + kg * 8];
      b[i] = *(const bf16x8*)&Bs[(wn * 64 + i * 16 + lm) * 40 + kg * 8];
    }
#pragma unroll
    for (int i = 0; i < 4; ++i)
#pragma unroll
      for (int j = 0; j < 4; ++j)
        acc[i][j] = __builtin_amdgcn_mfma_f32_16x16x32_bf16(a[i], b[j], acc[i][j], 0, 0, 0);
    __syncthreads();
  }

  // epilogue: D[m][n], m = (lane>>4)*4 + reg (per 16-tile), n = lane&15
  int m0 = row0 + wm * 64, n0 = col0 + wn * 64;
#pragma unroll
  for (int i = 0; i < 4; ++i) {
#pragma unroll
    for (int reg = 0; reg < 4; ++reg) {
      int m = m0 + i * 16 + kg * 4 + reg;
      size_t obase = 0;
      if (MODE == 1) {
        int w = m / 49, nn = m - w * 49;
        int bi = w >> 6, wi = w & 63;
        int hw = wi >> 3, ww = wi & 7;
        int ti = nn / 7, tj = nn - ti * 7;
        int hf = (hw * 7 + ti + 3) % 56, wf = (ww * 7 + tj + 3) % 56;  // reverse roll(+3,+3)
        obase = ((size_t)bi * 3136 + hf * 56 + wf) * 384;
      }
#pragma unroll
      for (int j = 0; j < 4; ++j) {
        int cN = n0 + j * 16 + lm;
        float v = acc[i][j][reg] + bias[cN];
        if (MODE == 0) {
          ((bf16*)out_)[(size_t)m * N + cN] = f2b(v);
        } else if (MODE == 1) {
          float* O = (float*)out_;
          O[obase + cN] = v + resid[obase + cN];
        } else if (MODE == 2) {
          v = 0.5f * v * (1.f + erff(v * 0.7071067811865475f));
          ((bf16*)out_)[(size_t)m * N + cN] = f2b(v);
        } else {
          float* O = (float*)out_;
          O[(size_t)m * N + cN] = v + resid[(size_t)m * N + cN];
        }
      }
    }
  }
}

// ---------------- attention per (window, head), chunk-local ----------------
__global__ __launch_bounds__(256) void attn_kernel(const bf16* __restrict__ qkv_c,
                                                   const float* __restrict__ table,
                                                   bf16* __restrict__ attn_c,
                                                   int w_base) {
  int wh = blockIdx.x;                 // 0..CW2*12-1
  int wl = wh / 12, h = wh - wl * 12;
  int w = w_base + wl;
  int wi = w & 63;
  int hw = wi >> 3, ww = wi & 7;
  __shared__ float Qs[49][32], Ks[49][32], Vs[49][32];
  __shared__ float S[49][50];
  int tid = threadIdx.x;
  const bf16* base = qkv_c + (size_t)wl * 49 * 1152 + h * 32;
  for (int idx = tid; idx < 1568; idx += 256) {
    int n = idx >> 5, d = idx & 31;
    const bf16* rowp = base + (size_t)n * 1152 + d;
    Qs[n][d] = b2f(rowp[0]);
    Ks[n][d] = b2f(rowp[384]);
    Vs[n][d] = b2f(rowp[768]);
  }
  __syncthreads();
  for (int e = tid; e < 2401; e += 256) {
    int i = e / 49, j = e - i * 49;
    float dot = 0.f;
#pragma unroll
    for (int d = 0; d < 32; ++d) dot += Qs[i][d] * Ks[j][d];
    int yi = i / 7, xi = i - yi * 7;
    int yj = j / 7, xj = j - yj * 7;
    int ridx = (yi - yj + 6) * 13 + (xi - xj + 6);
    float bias = table[ridx * 12 + h];
    int hri = hw * 7 + yi, wri = ww * 7 + xi;
    int hrj = hw * 7 + yj, wrj = ww * 7 + xj;
    int ri = (hri < 49 ? 0 : (hri < 53 ? 1 : 2)) * 3 + (wri < 49 ? 0 : (wri < 53 ? 1 : 2));
    int rj = (hrj < 49 ? 0 : (hrj < 53 ? 1 : 2)) * 3 + (wrj < 49 ? 0 : (wrj < 53 ? 1 : 2));
    float mask = (ri == rj) ? 0.f : -100.f;
    S[i][j] = SCALE_ * dot + bias + mask;
  }
  __syncthreads();
  if (tid < 49) {
    float mx = -1e30f;
    for (int j = 0; j < 49; ++j) mx = fmaxf(mx, S[tid][j]);
    float sum = 0.f;
    for (int j = 0; j < 49; ++j) { float e = expf(S[tid][j] - mx); S[tid][j] = e; sum += e; }
    float inv = 1.f / sum;
    for (int j = 0; j < 49; ++j) S[tid][j] *= inv;
  }
  __syncthreads();
  for (int e = tid; e < 1568; e += 256) {
    int n = e >> 5, d = e & 31;
    float o = 0.f;
    for (int j = 0; j < 49; ++j) o += S[n][j] * Vs[j][d];
    attn_c[((size_t)wl * 49 + n) * 384 + h * 32 + d] = f2b(o);
  }
}

extern "C" void kernel_launch(void* const* d_in, const int* in_sizes, int n_in,
                              void* d_out, int out_size, void* d_ws, size_t ws_size,
                              hipStream_t stream) {
  const float* x      = (const float*)d_in[0];
  const float* ln1_g  = (const float*)d_in[1];
  const float* ln1_b  = (const float*)d_in[2];
  const float* ln2_g  = (const float*)d_in[3];
  const float* ln2_b  = (const float*)d_in[4];
  const float* qkv_w  = (const float*)d_in[5];
  const float* qkv_b  = (const float*)d_in[6];
  const float* proj_w = (const float*)d_in[7];
  const float* proj_b = (const float*)d_in[8];
  const float* mlp_w1 = (const float*)d_in[9];
  const float* mlp_b1 = (const float*)d_in[10];
  const float* mlp_w2 = (const float*)d_in[11];
  const float* mlp_b2 = (const float*)d_in[12];
  const float* rel_tb = (const float*)d_in[13];

  char* ws = (char*)d_ws;
  // region0: 38,535,168 B — wins / attn_out (in-place rows) / ln2o
  ushort_t* r0 = (ushort_t*)(ws + 0);
  // region1: 77,070,336 B — qkv half-chunk (57.8MB) / hidden half-chunk (77MB)
  ushort_t* r1 = (ushort_t*)(ws + 38535168ull);
  // region2: bf16 transposed weights (3.54MB). Peak ws = 119,144,448 B (< proven 144.5MB).
  ushort_t* wq = (ushort_t*)(ws + 115605504ull);       // [1152,384]
  ushort_t* wp = wq + 442368;                          // [384,384]
  ushort_t* w1 = wp + 147456;                          // [1536,384]
  ushort_t* w2 = w1 + 589824;                          // [384,1536]
  float* out = (float*)d_out;                          // fp32; doubles as x1 residual

  // 0. weight transpose+convert (graph-safe: same work every call)
  wt_bf16<<<1728, 256, 0, stream>>>(qkv_w, wq, 384, 1152);
  wt_bf16<<<576, 256, 0, stream>>>(proj_w, wp, 384, 384);
  wt_bf16<<<2304, 256, 0, stream>>>(mlp_w1, w1, 384, 1536);
  wt_bf16<<<2304, 256, 0, stream>>>(mlp_w2, w2, 1536, 384);

  // 1. LN1 + shift + partition (full)
  ln1_kernel<<<TOKENS, 64, 0, stream>>>(x, ln1_g, ln1_b, (bf16*)r0);

  // 2+3. QKV GEMM + attention, 2 window-chunks (attn writes in-place over its wins rows)
  for (int c = 0; c < 2; ++c) {
    ushort_t* winc = r0 + (size_t)c * CROWS2 * 384;
    mfma_gemm<0><<<dim3(CROWS2 / 128, 9), 256, 0, stream>>>(
        winc, wq, qkv_b, 1152, 384, nullptr, (void*)r1);
    attn_kernel<<<CW2 * 12, 256, 0, stream>>>((bf16*)r1, rel_tb, (bf16*)winc, c * CW2);
  }

  // 4. proj GEMM + window-reverse + reverse-roll + residual -> d_out (x1, fp32)
  mfma_gemm<1><<<dim3(TOKENS / 128, 3), 256, 0, stream>>>(
      r0, wp, proj_b, 384, 384, x, (void*)out);

  // 5. LN2 (d_out -> region0 bf16)
  ln2_kernel<<<TOKENS, 64, 0, stream>>>(out, ln2_g, ln2_b, (bf16*)r0);

  // 6+7. MLP, 2 token-chunks (in-place residual on d_out)
  for (int c = 0; c < 2; ++c) {
    ushort_t* lc = r0 + (size_t)c * CROWS2 * 384;
    float* oc = out + (size_t)c * CROWS2 * 384;
    mfma_gemm<2><<<dim3(CROWS2 / 128, 12), 256, 0, stream>>>(
        lc, w1, mlp_b1, 1536, 384, nullptr, (void*)r1);
    mfma_gemm<3><<<dim3(CROWS2 / 128, 3), 256, 0, stream>>>(
        r1, w2, mlp_b2, 384, 1536, oc, (void*)oc);
  }
}

// Round 6
// 704.898 us; speedup vs baseline: 6.5701x; 1.3538x over previous
//
#include <hip/hip_runtime.h>
#include <hip/hip_bf16.h>
#include <math.h>

typedef __hip_bfloat16 bf16;
typedef unsigned short ushort_t;
typedef __bf16 bf16x8 __attribute__((ext_vector_type(8)));
typedef float f32x4 __attribute__((ext_vector_type(4)));

#define TOKENS 50176        // 16 * 3136
#define CW2 512             // windows per chunk (2 chunks)
#define CROWS2 (CW2 * 49)   // 25088 rows per chunk
#define SCALE_ 0.17677669529663687f  // 32^-0.5

__device__ __forceinline__ float b2f(bf16 v) { return __bfloat162float(v); }
__device__ __forceinline__ bf16  f2b(float v) { return __float2bfloat16(v); }

// ---------------- weight convert: Wt[n][k] = bf16(W[k][n]) ----------------
__global__ __launch_bounds__(256) void wt_bf16(const float* __restrict__ W,
                                               ushort_t* __restrict__ Wt,
                                               int K, int N) {
  int idx = blockIdx.x * 256 + threadIdx.x;
  if (idx >= K * N) return;
  int n = idx / K, k = idx - n * K;
  bf16 h = f2b(W[(size_t)k * N + n]);
  Wt[idx] = *(ushort_t*)&h;
}

// ---------------- LN1 + cyclic shift(-3,+3) + window partition (full) ----------------
__global__ __launch_bounds__(64) void ln1_kernel(const float* __restrict__ x,
                                                 const float* __restrict__ g,
                                                 const float* __restrict__ bta,
                                                 bf16* __restrict__ wins) {
  int t = blockIdx.x;
  int lane = threadIdx.x;
  int w = t / 49, n = t - w * 49;
  int bi = w >> 6, wi = w & 63;
  int hw = wi >> 3, ww = wi & 7;
  int ti = n / 7, tj = n - ti * 7;
  int hr = hw * 7 + ti, wr = ww * 7 + tj;
  int hs = (hr + 3) % 56;          // roll -3 on h
  int wsc = (wr + 53) % 56;        // roll +3 on w
  const float* row = x + ((size_t)bi * 3136 + hs * 56 + wsc) * 384;
  float v[6];
  float s = 0.f, s2 = 0.f;
#pragma unroll
  for (int j = 0; j < 6; ++j) {
    v[j] = row[lane + 64 * j];
    s += v[j]; s2 += v[j] * v[j];
  }
#pragma unroll
  for (int m = 32; m >= 1; m >>= 1) {
    s  += __shfl_xor(s, m, 64);
    s2 += __shfl_xor(s2, m, 64);
  }
  float mu = s * (1.f / 384.f);
  float var = s2 * (1.f / 384.f) - mu * mu;
  float rstd = rsqrtf(var + 1e-3f);
  bf16* orow = wins + (size_t)t * 384;
#pragma unroll
  for (int j = 0; j < 6; ++j) {
    int c = lane + 64 * j;
    orow[c] = f2b((v[j] - mu) * rstd * g[c] + bta[c]);
  }
}

// ---------------- LN2: fp32 rows -> bf16 ----------------
__global__ __launch_bounds__(64) void ln2_kernel(const float* __restrict__ x1,
                                                 const float* __restrict__ g,
                                                 const float* __restrict__ bta,
                                                 bf16* __restrict__ out) {
  int t = blockIdx.x;
  int lane = threadIdx.x;
  const float* row = x1 + (size_t)t * 384;
  float v[6];
  float s = 0.f, s2 = 0.f;
#pragma unroll
  for (int j = 0; j < 6; ++j) {
    v[j] = row[lane + 64 * j];
    s += v[j]; s2 += v[j] * v[j];
  }
#pragma unroll
  for (int m = 32; m >= 1; m >>= 1) {
    s  += __shfl_xor(s, m, 64);
    s2 += __shfl_xor(s2, m, 64);
  }
  float mu = s * (1.f / 384.f);
  float var = s2 * (1.f / 384.f) - mu * mu;
  float rstd = rsqrtf(var + 1e-3f);
  bf16* orow = out + (size_t)t * 384;
#pragma unroll
  for (int j = 0; j < 6; ++j) {
    int c = lane + 64 * j;
    orow[c] = f2b((v[j] - mu) * rstd * g[c] + bta[c]);
  }
}

// ---------------- MFMA GEMM: C[M,N] = A[M,K](bf16) @ Bt[N,K](bf16)^T + bias ----------------
template<int MODE>
__global__ __launch_bounds__(256) void mfma_gemm(
    const ushort_t* __restrict__ A, const ushort_t* __restrict__ Bt,
    const float* __restrict__ bias, int N, int K,
    const float* __restrict__ resid, void* __restrict__ out_) {
  __shared__ ushort_t As[128 * 40];
  __shared__ ushort_t Bs[128 * 40];
  int tid = threadIdx.x;
  int lane = tid & 63, wv = tid >> 6;
  int wm = wv >> 1, wn = wv & 1;
  int lm = lane & 15, kg = lane >> 4;
  int row0 = blockIdx.x * 128, col0 = blockIdx.y * 128;
  f32x4 acc[4][4];
#pragma unroll
  for (int i = 0; i < 4; ++i)
#pragma unroll
    for (int j = 0; j < 4; ++j) acc[i][j] = (f32x4){0.f, 0.f, 0.f, 0.f};

  for (int k0 = 0; k0 < K; k0 += 32) {
#pragma unroll
    for (int it = 0; it < 2; ++it) {
      int lin = it * 256 + tid;
      int r = lin >> 2, kq = (lin & 3) * 8;
      *(int4*)&As[r * 40 + kq] = *(const int4*)&A[(size_t)(row0 + r) * K + k0 + kq];
      *(int4*)&Bs[r * 40 + kq] = *(const int4*)&Bt[(size_t)(col0 + r) * K + k0 + kq];
    }
    __syncthreads();
    bf16x8 a[4], b[4];
#pragma unroll
    for (int i = 0; i < 4; ++i) {
      a[i] = *(const bf16x8*)&As[(wm * 64 + i * 16 + lm) * 40 + kg * 8];
      b[i] = *(const bf16x8*)&Bs[(wn * 64 + i * 16 + lm) * 40 + kg * 8];
    }
#pragma unroll
    for (int i = 0; i < 4; ++i)
#pragma unroll
      for (int j = 0; j < 4; ++j)
        acc[i][j] = __builtin_amdgcn_mfma_f32_16x16x32_bf16(a[i], b[j], acc[i][j], 0, 0, 0);
    __syncthreads();
  }

  int m0 = row0 + wm * 64, n0 = col0 + wn * 64;
#pragma unroll
  for (int i = 0; i < 4; ++i) {
#pragma unroll
    for (int reg = 0; reg < 4; ++reg) {
      int m = m0 + i * 16 + kg * 4 + reg;
      size_t obase = 0;
      if (MODE == 1) {
        int w = m / 49, nn = m - w * 49;
        int bi = w >> 6, wi = w & 63;
        int hw = wi >> 3, ww = wi & 7;
        int ti = nn / 7, tj = nn - ti * 7;
        int hf = (hw * 7 + ti + 3) % 56, wf = (ww * 7 + tj + 3) % 56;
        obase = ((size_t)bi * 3136 + hf * 56 + wf) * 384;
      }
#pragma unroll
      for (int j = 0; j < 4; ++j) {
        int cN = n0 + j * 16 + lm;
        float v = acc[i][j][reg] + bias[cN];
        if (MODE == 0) {
          ((bf16*)out_)[(size_t)m * N + cN] = f2b(v);
        } else if (MODE == 1) {
          float* O = (float*)out_;
          O[obase + cN] = v + resid[obase + cN];
        } else if (MODE == 2) {
          v = 0.5f * v * (1.f + erff(v * 0.7071067811865475f));
          ((bf16*)out_)[(size_t)m * N + cN] = f2b(v);
        } else {
          float* O = (float*)out_;
          O[(size_t)m * N + cN] = v + resid[(size_t)m * N + cN];
        }
      }
    }
  }
}

// ---------------- MFMA attention: block = (window, head-group of 3) ----------------
// Per head: QK^T (4 mfma/wave), in-register softmax (+bias+mask), P->LDS, PV (4 mfma/wave).
__global__ __launch_bounds__(256) void attn_mfma(const ushort_t* __restrict__ qkv_c,
                                                 const float* __restrict__ table,
                                                 ushort_t* __restrict__ attn_c,
                                                 int w_base) {
  int wl = blockIdx.x >> 2, hg = blockIdx.x & 3;   // 512 windows x 4 head-groups
  int w = w_base + wl;
  int wi = w & 63;
  int hw = wi >> 3, ww = wi & 7;
  __shared__ ushort_t Qs[64 * 40];   // [row m][d], stride 40 (16B-aligned rows)
  __shared__ ushort_t Ks[64 * 40];   // [row n][d]
  __shared__ ushort_t Vt[32 * 72];   // [dcol][key], stride 72
  __shared__ ushort_t Ps[64 * 72];   // [row m][key], stride 72
  __shared__ float bias_s[169 * 12];
  int tid = threadIdx.x;
  int lane = tid & 63, wv = tid >> 6;              // wv = 16-row strip
  int lm = lane & 15, kg = lane >> 4;

  // zero-fill staging pads once (rows/cols >= 49 stay zero across heads)
  for (int i = tid; i < 64 * 40; i += 256) { Qs[i] = 0; Ks[i] = 0; }
  for (int i = tid; i < 32 * 72; i += 256) Vt[i] = 0;
  for (int i = tid; i < 169 * 12; i += 256) bias_s[i] = table[i];
  __syncthreads();

  for (int hh = 0; hh < 3; ++hh) {
    int h = hg * 3 + hh;
    // stage Q,K,V(transposed) for this head: 392 vec4 jobs
    const ushort_t* base = qkv_c + (size_t)wl * 49 * 1152 + h * 32;
    for (int idx = tid; idx < 392; idx += 256) {
      int n = idx >> 3, d0 = (idx & 7) * 4;
      const ushort_t* p = base + (size_t)n * 1152 + d0;
      ushort4 q = *(const ushort4*)(p);
      ushort4 k = *(const ushort4*)(p + 384);
      ushort4 v = *(const ushort4*)(p + 768);
      *(ushort4*)&Qs[n * 40 + d0] = q;
      *(ushort4*)&Ks[n * 40 + d0] = k;
      Vt[(d0 + 0) * 72 + n] = v.x;
      Vt[(d0 + 1) * 72 + n] = v.y;
      Vt[(d0 + 2) * 72 + n] = v.z;
      Vt[(d0 + 3) * 72 + n] = v.w;
    }
    __syncthreads();

    // QK^T: wave's 16-row strip x 64 cols
    bf16x8 qa = *(const bf16x8*)&Qs[(wv * 16 + lm) * 40 + kg * 8];
    f32x4 sacc[4];
#pragma unroll
    for (int jt = 0; jt < 4; ++jt) {
      bf16x8 kb = *(const bf16x8*)&Ks[(jt * 16 + lm) * 40 + kg * 8];
      sacc[jt] = __builtin_amdgcn_mfma_f32_16x16x32_bf16(
          qa, kb, (f32x4){0.f, 0.f, 0.f, 0.f}, 0, 0, 0);
    }

    // softmax rows: row = wv*16 + kg*4 + reg, col = jt*16 + lm
    int i_base = wv * 16 + kg * 4;
#pragma unroll
    for (int reg = 0; reg < 4; ++reg) {
      int i = i_base + reg;
      int ii = (i < 49) ? i : 0;
      int yi = ii / 7, xi = ii - yi * 7;
      int hri = hw * 7 + yi, wri = ww * 7 + xi;
      int ri = (hri < 49 ? 0 : (hri < 53 ? 1 : 2)) * 3 + (wri < 49 ? 0 : (wri < 53 ? 1 : 2));
      float sv[4];
      float mx = -1e30f;
#pragma unroll
      for (int jt = 0; jt < 4; ++jt) {
        int j = jt * 16 + lm;
        int jj = (j < 49) ? j : 0;
        int yj = jj / 7, xj = jj - yj * 7;
        int hrj = hw * 7 + yj, wrj = ww * 7 + xj;
        int rj = (hrj < 49 ? 0 : (hrj < 53 ? 1 : 2)) * 3 + (wrj < 49 ? 0 : (wrj < 53 ? 1 : 2));
        int ridx = (yi - yj + 6) * 13 + (xi - xj + 6);
        float s = sacc[jt][reg] * SCALE_ + bias_s[ridx * 12 + h] + ((ri == rj) ? 0.f : -100.f);
        sv[jt] = (j < 49) ? s : -1e30f;
        mx = fmaxf(mx, sv[jt]);
      }
#pragma unroll
      for (int msk = 1; msk < 16; msk <<= 1) mx = fmaxf(mx, __shfl_xor(mx, msk, 64));
      float sm = 0.f;
#pragma unroll
      for (int jt = 0; jt < 4; ++jt) {
        float e = ((jt * 16 + lm) < 49) ? __expf(sv[jt] - mx) : 0.f;
        sv[jt] = e; sm += e;
      }
#pragma unroll
      for (int msk = 1; msk < 16; msk <<= 1) sm += __shfl_xor(sm, msk, 64);
      float inv = 1.f / sm;   // sm >= 1 (max-subtracted; every row has >=1 valid col)
#pragma unroll
      for (int jt = 0; jt < 4; ++jt) {
        bf16 pb = f2b(sv[jt] * inv);
        Ps[(size_t)i * 72 + jt * 16 + lm] = *(ushort_t*)&pb;
      }
    }
    // PV: O_strip[16][32] = P_strip[16][64] @ V[64][32] (own strip only -> no barrier)
    f32x4 oacc[2] = {(f32x4){0.f, 0.f, 0.f, 0.f}, (f32x4){0.f, 0.f, 0.f, 0.f}};
#pragma unroll
    for (int ks = 0; ks < 2; ++ks) {
      bf16x8 pa = *(const bf16x8*)&Ps[(wv * 16 + lm) * 72 + ks * 32 + kg * 8];
#pragma unroll
      for (int dt = 0; dt < 2; ++dt) {
        bf16x8 vb = *(const bf16x8*)&Vt[(dt * 16 + lm) * 72 + ks * 32 + kg * 8];
        oacc[dt] = __builtin_amdgcn_mfma_f32_16x16x32_bf16(pa, vb, oacc[dt], 0, 0, 0);
      }
    }
#pragma unroll
    for (int reg = 0; reg < 4; ++reg) {
      int r = i_base + reg;
      if (r < 49) {
#pragma unroll
        for (int dt = 0; dt < 2; ++dt) {
          bf16 ob = f2b(oacc[dt][reg]);
          attn_c[((size_t)wl * 49 + r) * 384 + h * 32 + dt * 16 + lm] = *(ushort_t*)&ob;
        }
      }
    }
    __syncthreads();   // protect Qs/Ks/Vt before next head's restage
  }
}

extern "C" void kernel_launch(void* const* d_in, const int* in_sizes, int n_in,
                              void* d_out, int out_size, void* d_ws, size_t ws_size,
                              hipStream_t stream) {
  const float* x      = (const float*)d_in[0];
  const float* ln1_g  = (const float*)d_in[1];
  const float* ln1_b  = (const float*)d_in[2];
  const float* ln2_g  = (const float*)d_in[3];
  const float* ln2_b  = (const float*)d_in[4];
  const float* qkv_w  = (const float*)d_in[5];
  const float* qkv_b  = (const float*)d_in[6];
  const float* proj_w = (const float*)d_in[7];
  const float* proj_b = (const float*)d_in[8];
  const float* mlp_w1 = (const float*)d_in[9];
  const float* mlp_b1 = (const float*)d_in[10];
  const float* mlp_w2 = (const float*)d_in[11];
  const float* mlp_b2 = (const float*)d_in[12];
  const float* rel_tb = (const float*)d_in[13];

  char* ws = (char*)d_ws;
  ushort_t* r0 = (ushort_t*)(ws + 0);                  // 38.5MB: wins / attn_out / ln2o
  ushort_t* r1 = (ushort_t*)(ws + 38535168ull);        // 77MB: qkv chunk / hidden chunk
  ushort_t* wq = (ushort_t*)(ws + 115605504ull);       // bf16 W^T: [1152,384]
  ushort_t* wp = wq + 442368;                          // [384,384]
  ushort_t* w1 = wp + 147456;                          // [1536,384]
  ushort_t* w2 = w1 + 589824;                          // [384,1536]
  float* out = (float*)d_out;

  wt_bf16<<<1728, 256, 0, stream>>>(qkv_w, wq, 384, 1152);
  wt_bf16<<<576, 256, 0, stream>>>(proj_w, wp, 384, 384);
  wt_bf16<<<2304, 256, 0, stream>>>(mlp_w1, w1, 384, 1536);
  wt_bf16<<<2304, 256, 0, stream>>>(mlp_w2, w2, 1536, 384);

  ln1_kernel<<<TOKENS, 64, 0, stream>>>(x, ln1_g, ln1_b, (bf16*)r0);

  for (int c = 0; c < 2; ++c) {
    ushort_t* winc = r0 + (size_t)c * CROWS2 * 384;
    mfma_gemm<0><<<dim3(CROWS2 / 128, 9), 256, 0, stream>>>(
        winc, wq, qkv_b, 1152, 384, nullptr, (void*)r1);
    attn_mfma<<<CW2 * 4, 256, 0, stream>>>(r1, rel_tb, winc, c * CW2);
  }

  mfma_gemm<1><<<dim3(TOKENS / 128, 3), 256, 0, stream>>>(
      r0, wp, proj_b, 384, 384, x, (void*)out);

  ln2_kernel<<<TOKENS, 64, 0, stream>>>(out, ln2_g, ln2_b, (bf16*)r0);

  for (int c = 0; c < 2; ++c) {
    ushort_t* lc = r0 + (size_t)c * CROWS2 * 384;
    float* oc = out + (size_t)c * CROWS2 * 384;
    mfma_gemm<2><<<dim3(CROWS2 / 128, 12), 256, 0, stream>>>(
        lc, w1, mlp_b1, 1536, 384, nullptr, (void*)r1);
    mfma_gemm<3><<<dim3(CROWS2 / 128, 3), 256, 0, stream>>>(
        r1, w2, mlp_b2, 384, 1536, oc, (void*)oc);
  }
}